// Round 11
// baseline (153.040 us; speedup 1.0000x reference)
//
#include <hip/hip_runtime.h>
#include <cmath>

#define T_LEN 262144
#define NROW 8
#define NT 384                       /* threads per block */
#define EXT 3072                     /* positions per tile (8 per thread) */
#define HALO 576
#define TILE (EXT - HALO)            /* 2496 */
#define PB 106                       /* ceil(262144/2496) */
#define PAD 32                       /* left pad floats (= max 4*D) */
#define CH 4096
#define RB (T_LEN / CH)              /* 64 */
#define NB2 (NROW * RB)              /* 512 */

#define NEG2LOG2E -2.885390082f
#define NEGLOG2E  -1.4426950409f

#if __has_builtin(__builtin_amdgcn_exp2f)
#define EXP2(x) __builtin_amdgcn_exp2f(x)
#else
#define EXP2(x) __expf(0.6931471805599453f * (x))
#endif

typedef float f32x2 __attribute__((ext_vector_type(2)));
typedef float f32x4 __attribute__((ext_vector_type(4)));

__device__ __forceinline__ float fast_rcp(float x) { return __builtin_amdgcn_rcpf(x); }

__device__ __forceinline__ f32x2 exp2v(f32x2 x) {
    f32x2 r; r.x = EXP2(x.x); r.y = EXP2(x.y); return r;
}
__device__ __forceinline__ f32x2 rcpv(f32x2 x) {
    f32x2 r; r.x = fast_rcp(x.x); r.y = fast_rcp(x.y); return r;
}
// z = tanh(af)*sigmoid(ag) = (1-u)/((1+u)(1+w)), u=e^{-2af}, w=e^{-ag}
__device__ __forceinline__ f32x2 gatedv(f32x2 af, f32x2 ag) {
    const f32x2 u = exp2v(af * NEG2LOG2E);
    const f32x2 w = exp2v(ag * NEGLOG2E);
    return (1.0f - u) * rcpv((1.0f + u) * (1.0f + w));
}

// Gated residual layer, 8 positions/thread in registers. Even dilation D:
// all taps are pair-aligned; only the 4*D-float left halo comes from LDS
// (D x b128), write-back is 2 x b128. CUT = progressive dead-halo bound
// (multiple of 8 -> whole thread dead or alive).
template<int D, int CUT, bool WB>
__device__ __forceinline__ void layer8(
    int k,
    const float* __restrict__ fw, const float* __restrict__ fb,
    const float* __restrict__ gw, const float* __restrict__ gb,
    const float* __restrict__ rw, const float* __restrict__ rb,
    const float* __restrict__ src, float* __restrict__ dst,
    f32x2 (&h)[4], f32x2 (&skip)[4], int base)
{
    const float f0 = fw[k*5+0], f1 = fw[k*5+1], f2 = fw[k*5+2], f3 = fw[k*5+3], f4 = fw[k*5+4];
    const float fbk = fb[k];
    const float g0 = gw[k*5+0], g1 = gw[k*5+1], g2 = gw[k*5+2], g3 = gw[k*5+3], g4 = gw[k*5+4];
    const float gbk = gb[k];
    const float rwk = rw[k], rbk = rb[k];

    if (base >= CUT) {                       // thread alive at this layer
        f32x2 halo[2*D];                     // 4*D floats = 2*D pairs
        #pragma unroll
        for (int j = 0; j < D; ++j) {
            const f32x4 t4 = *(const f32x4*)&src[base - 4*D + 4*j];
            f32x2 lo; lo.x = t4.x; lo.y = t4.y;
            f32x2 hi; hi.x = t4.z; hi.y = t4.w;
            halo[2*j]   = lo;
            halo[2*j+1] = hi;
        }
        #pragma unroll
        for (int p = 3; p >= 0; --p) {       // descending: in-place safe
            const int r4 = p - 4*(D/2);
            const int r3 = p - 3*(D/2);
            const int r2 = p - 2*(D/2);
            const int r1 = p - 1*(D/2);
            const f32x2 v0 = (r4 >= 0) ? h[r4] : halo[2*D + r4];
            const f32x2 v1 = (r3 >= 0) ? h[r3] : halo[2*D + r3];
            const f32x2 v2 = (r2 >= 0) ? h[r2] : halo[2*D + r2];
            const f32x2 v3 = (r1 >= 0) ? h[r1] : halo[2*D + r1];
            const f32x2 v4 = h[p];

            f32x2 af = fbk + f0 * v0;
            af = f1 * v1 + af;
            af = f2 * v2 + af;
            af = f3 * v3 + af;
            af = f4 * v4 + af;
            f32x2 ag = gbk + g0 * v0;
            ag = g1 * v1 + ag;
            ag = g2 * v2 + ag;
            ag = g3 * v3 + ag;
            ag = g4 * v4 + ag;

            const f32x2 z = gatedv(af, ag);
            skip[p] += z;
            if (WB) h[p] = (z * rwk + rbk) + v4;
        }
        if (WB) {
            f32x4 lo; lo.x = h[0].x; lo.y = h[0].y; lo.z = h[1].x; lo.w = h[1].y;
            f32x4 hi; hi.x = h[2].x; hi.y = h[2].y; hi.z = h[3].x; hi.w = h[3].y;
            *(f32x4*)&dst[base]     = lo;
            *(f32x4*)&dst[base + 4] = hi;
        }
    }
    if (WB) __syncthreads();
}

// d=1 gated layer (layer 0): 12-float register window (4 halo + 8 own).
__device__ __forceinline__ void layer8_d1(
    const float* __restrict__ fw, const float* __restrict__ fb,
    const float* __restrict__ gw, const float* __restrict__ gb,
    const float* __restrict__ rw, const float* __restrict__ rb,
    const float* __restrict__ src, float* __restrict__ dst,
    f32x2 (&h)[4], f32x2 (&skip)[4], int base)
{
    const float f0 = fw[0], f1 = fw[1], f2 = fw[2], f3 = fw[3], f4 = fw[4];
    const float fbk = fb[0];
    const float g0 = gw[0], g1 = gw[1], g2 = gw[2], g3 = gw[3], g4 = gw[4];
    const float gbk = gb[0];
    const float rwk = rw[0], rbk = rb[0];

    const f32x4 hl = *(const f32x4*)&src[base - 4];
    const float w[12] = {hl.x, hl.y, hl.z, hl.w,
                         h[0].x, h[0].y, h[1].x, h[1].y,
                         h[2].x, h[2].y, h[3].x, h[3].y};
    #pragma unroll
    for (int p = 0; p < 4; ++p) {
        f32x2 v0; v0.x = w[2*p+0]; v0.y = w[2*p+1];
        f32x2 v1; v1.x = w[2*p+1]; v1.y = w[2*p+2];
        f32x2 v2; v2.x = w[2*p+2]; v2.y = w[2*p+3];
        f32x2 v3; v3.x = w[2*p+3]; v3.y = w[2*p+4];
        const f32x2 v4 = h[p];

        f32x2 af = fbk + f0 * v0;
        af = f1 * v1 + af;
        af = f2 * v2 + af;
        af = f3 * v3 + af;
        af = f4 * v4 + af;
        f32x2 ag = gbk + g0 * v0;
        ag = g1 * v1 + ag;
        ag = g2 * v2 + ag;
        ag = g3 * v3 + ag;
        ag = g4 * v4 + ag;

        const f32x2 z = gatedv(af, ag);
        skip[p] += z;
        h[p] = (z * rwk + rbk) + v4;
    }
    f32x4 lo; lo.x = h[0].x; lo.y = h[0].y; lo.z = h[1].x; lo.w = h[1].y;
    f32x4 hi; hi.x = h[2].x; hi.y = h[2].y; hi.z = h[3].x; hi.w = h[3].y;
    *(f32x4*)&dst[base]     = lo;
    *(f32x4*)&dst[base + 4] = hi;
    __syncthreads();
}

// ---------------------------------------------------------------------------
__global__ __launch_bounds__(NT, 4)
void k_wavenet(const float* __restrict__ x,
               const float* __restrict__ cw,  const float* __restrict__ cb,
               const float* __restrict__ fw,  const float* __restrict__ fb,
               const float* __restrict__ gw,  const float* __restrict__ gb,
               const float* __restrict__ rw,  const float* __restrict__ rb,
               const float* __restrict__ c1w, const float* __restrict__ c1b,
               const float* __restrict__ c2w, const float* __restrict__ c2b,
               float* __restrict__ eout, float* __restrict__ partsum)
{
    __shared__ __align__(16) float rA[PAD + EXT];
    __shared__ __align__(16) float rB[PAD + EXT];
    __shared__ float reds[NT / 64];
    float* A = rA + PAD;
    float* B = rB + PAD;

    const int tid  = threadIdx.x;
    const int base = 8 * tid;
    const int row  = blockIdx.x / PB;
    const int tile = blockIdx.x % PB;
    const int t0   = tile * TILE;

    if (tid < PAD / 4) {                 // zero both pads (8 threads x f32x4)
        f32x4 z4; z4.x = 0.f; z4.y = 0.f; z4.z = 0.f; z4.w = 0.f;
        *(f32x4*)&rA[4*tid] = z4;
        *(f32x4*)&rB[4*tid] = z4;
    }

    const float* xr = x + (size_t)row * T_LEN;

    // stage x tile into A (coalesced f32x4)
    if (t0 - HALO >= 0 && t0 - HALO + EXT <= T_LEN) {
        #pragma unroll
        for (int j = 0; j < 2; ++j) {
            const int s = tid + j * NT;
            *(f32x4*)&A[4*s] = *(const f32x4*)&xr[t0 - HALO + 4*s];
        }
    } else {
        #pragma unroll
        for (int j = 0; j < 2; ++j) {
            const int s = tid + j * NT;
            const int g = t0 - HALO + 4*s;
            f32x4 v;
            v.x = (g   >= 0 && g   < T_LEN) ? xr[g]   : 0.0f;
            v.y = (g+1 >= 0 && g+1 < T_LEN) ? xr[g+1] : 0.0f;
            v.z = (g+2 >= 0 && g+2 < T_LEN) ? xr[g+2] : 0.0f;
            v.w = (g+3 >= 0 && g+3 < T_LEN) ? xr[g+3] : 0.0f;
            *(f32x4*)&A[4*s] = v;
        }
    }
    __syncthreads();

    // own 8 positions -> registers
    f32x2 h[4], skip[4];
    {
        const f32x4 a = *(const f32x4*)&A[base];
        const f32x4 b = *(const f32x4*)&A[base + 4];
        h[0].x = a.x; h[0].y = a.y; h[1].x = a.z; h[1].y = a.w;
        h[2].x = b.x; h[2].y = b.y; h[3].x = b.z; h[3].y = b.w;
        #pragma unroll
        for (int p = 0; p < 4; ++p) { skip[p].x = 0.f; skip[p].y = 0.f; }
    }

    // initial causal conv (d=1): A -> B
    {
        const float q0 = cw[0], q1 = cw[1], q2 = cw[2], q3 = cw[3], q4 = cw[4];
        const float qb = cb[0];
        const f32x4 hl = *(const f32x4*)&A[base - 4];
        const float w[12] = {hl.x, hl.y, hl.z, hl.w,
                             h[0].x, h[0].y, h[1].x, h[1].y,
                             h[2].x, h[2].y, h[3].x, h[3].y};
        #pragma unroll
        for (int p = 0; p < 4; ++p) {
            f32x2 v0; v0.x = w[2*p+0]; v0.y = w[2*p+1];
            f32x2 v1; v1.x = w[2*p+1]; v1.y = w[2*p+2];
            f32x2 v2; v2.x = w[2*p+2]; v2.y = w[2*p+3];
            f32x2 v3; v3.x = w[2*p+3]; v3.y = w[2*p+4];
            f32x2 acc = qb + q0 * v0;
            acc = q1 * v1 + acc;
            acc = q2 * v2 + acc;
            acc = q3 * v3 + acc;
            acc = q4 * h[p] + acc;
            h[p] = acc;
        }
        f32x4 lo; lo.x = h[0].x; lo.y = h[0].y; lo.z = h[1].x; lo.w = h[1].y;
        f32x4 hi; hi.x = h[2].x; hi.y = h[2].y; hi.z = h[3].x; hi.w = h[3].y;
        *(f32x4*)&B[base]     = lo;
        *(f32x4*)&B[base + 4] = hi;
        __syncthreads();
    }

    // layer 0 (d=1): B -> A; then layers 1..29 alternate, one barrier each.
    layer8_d1(fw, fb, gw, gb, rw, rb, B, A, h, skip, base);
    layer8<2,  16, true >( 1, fw, fb, gw, gb, rw, rb, A, B, h, skip, base);
    layer8<4,  32, true >( 2, fw, fb, gw, gb, rw, rb, B, A, h, skip, base);
    layer8<8,  64, true >( 3, fw, fb, gw, gb, rw, rb, A, B, h, skip, base);
    layer8<6,  88, true >( 4, fw, fb, gw, gb, rw, rb, B, A, h, skip, base);
    layer8<2,  96, true >( 5, fw, fb, gw, gb, rw, rb, A, B, h, skip, base);
    layer8<4, 112, true >( 6, fw, fb, gw, gb, rw, rb, B, A, h, skip, base);
    layer8<8, 144, true >( 7, fw, fb, gw, gb, rw, rb, A, B, h, skip, base);
    layer8<6, 168, true >( 8, fw, fb, gw, gb, rw, rb, B, A, h, skip, base);
    layer8<2, 176, true >( 9, fw, fb, gw, gb, rw, rb, A, B, h, skip, base);
    layer8<4, 192, true >(10, fw, fb, gw, gb, rw, rb, B, A, h, skip, base);
    layer8<8, 224, true >(11, fw, fb, gw, gb, rw, rb, A, B, h, skip, base);
    layer8<6, 248, true >(12, fw, fb, gw, gb, rw, rb, B, A, h, skip, base);
    layer8<2, 256, true >(13, fw, fb, gw, gb, rw, rb, A, B, h, skip, base);
    layer8<4, 272, true >(14, fw, fb, gw, gb, rw, rb, B, A, h, skip, base);
    layer8<8, 304, true >(15, fw, fb, gw, gb, rw, rb, A, B, h, skip, base);
    layer8<6, 328, true >(16, fw, fb, gw, gb, rw, rb, B, A, h, skip, base);
    layer8<2, 336, true >(17, fw, fb, gw, gb, rw, rb, A, B, h, skip, base);
    layer8<4, 352, true >(18, fw, fb, gw, gb, rw, rb, B, A, h, skip, base);
    layer8<8, 384, true >(19, fw, fb, gw, gb, rw, rb, A, B, h, skip, base);
    layer8<6, 408, true >(20, fw, fb, gw, gb, rw, rb, B, A, h, skip, base);
    layer8<2, 416, true >(21, fw, fb, gw, gb, rw, rb, A, B, h, skip, base);
    layer8<4, 432, true >(22, fw, fb, gw, gb, rw, rb, B, A, h, skip, base);
    layer8<8, 464, true >(23, fw, fb, gw, gb, rw, rb, A, B, h, skip, base);
    layer8<6, 488, true >(24, fw, fb, gw, gb, rw, rb, B, A, h, skip, base);
    layer8<2, 496, true >(25, fw, fb, gw, gb, rw, rb, A, B, h, skip, base);
    layer8<4, 512, true >(26, fw, fb, gw, gb, rw, rb, B, A, h, skip, base);
    layer8<8, 544, true >(27, fw, fb, gw, gb, rw, rb, A, B, h, skip, base);
    layer8<6, 568, true >(28, fw, fb, gw, gb, rw, rb, B, A, h, skip, base);
    layer8<2, 576, false>(29, fw, fb, gw, gb, rw, rb, A, B, h, skip, base);

    // epilogue: 1x1 convs + mu-law expand; write e = exp(v); partial sum
    const float w1 = c1w[0], b1 = c1b[0], w2 = c2w[0], b2 = c2b[0];
    float s = 0.0f;
    if (base >= HALO) {
        const int t = t0 + base - HALO;          // multiple of 8
        if (t < T_LEN) {
            float e8[8];
            #pragma unroll
            for (int p = 0; p < 4; ++p) {
                f32x2 sk = skip[p];
                float ox = fmaf(fmaxf(sk.x, 0.0f), w1, b1);
                float oy = fmaf(fmaxf(sk.y, 0.0f), w1, b1);
                ox = fmaf(fmaxf(ox, 0.0f), w2, b2);
                oy = fmaf(fmaxf(oy, 0.0f), w2, b2);
                float vx = fmaf(EXP2(8.0f * fabsf(ox)), (1.0f/255.0f), -(1.0f/255.0f));
                float vy = fmaf(EXP2(8.0f * fabsf(oy)), (1.0f/255.0f), -(1.0f/255.0f));
                vx = copysignf(vx, ox);
                vy = copysignf(vy, oy);
                const float ex = __expf(vx);
                const float ey = __expf(vy);
                e8[2*p] = ex; e8[2*p+1] = ey;
                s += ex + ey;
            }
            float* er = eout + (size_t)row * T_LEN + t;
            f32x4 lo; lo.x = e8[0]; lo.y = e8[1]; lo.z = e8[2]; lo.w = e8[3];
            f32x4 hi; hi.x = e8[4]; hi.y = e8[5]; hi.z = e8[6]; hi.w = e8[7];
            *(f32x4*)&er[0] = lo;
            *(f32x4*)&er[4] = hi;
        }
    }
    #pragma unroll
    for (int off = 32; off >= 1; off >>= 1) s += __shfl_xor(s, off, 64);
    if ((tid & 63) == 0) reds[tid >> 6] = s;
    __syncthreads();
    if (tid == 0) {
        float ss = 0.0f;
        #pragma unroll
        for (int w = 0; w < NT / 64; ++w) ss += reds[w];
        partsum[blockIdx.x] = ss;
    }
}

// ---------------------------------------------------------------------------
__global__ __launch_bounds__(256)
void k_scale(float* __restrict__ ebuf, const float* __restrict__ partsum)
{
    const int tid = threadIdx.x;
    const int row = blockIdx.x / RB;

    __shared__ float red[4];
    float s = 0.0f;
    for (int j = tid; j < PB; j += 256) s += partsum[row * PB + j];
    #pragma unroll
    for (int off = 32; off >= 1; off >>= 1) s += __shfl_xor(s, off, 64);
    if ((tid & 63) == 0) red[tid >> 6] = s;
    __syncthreads();
    const float tot = (red[0] + red[1]) + (red[2] + red[3]);
    const float inv = 1.0f / tot;

    float4* vp = (float4*)(ebuf + (size_t)blockIdx.x * CH);
    #pragma unroll
    for (int q = 0; q < 4; ++q) {
        float4 v = vp[tid + q * 256];
        v.x *= inv; v.y *= inv; v.z *= inv; v.w *= inv;
        vp[tid + q * 256] = v;
    }
}

// ---------------------------------------------------------------------------
extern "C" void kernel_launch(void* const* d_in, const int* in_sizes, int n_in,
                              void* d_out, int out_size, void* d_ws, size_t ws_size,
                              hipStream_t stream)
{
    const float* x   = (const float*)d_in[0];
    const float* cw  = (const float*)d_in[1];
    const float* cb  = (const float*)d_in[2];
    const float* fw  = (const float*)d_in[3];
    const float* fb  = (const float*)d_in[4];
    const float* gw  = (const float*)d_in[5];
    const float* gb  = (const float*)d_in[6];
    const float* rw  = (const float*)d_in[7];
    const float* rb  = (const float*)d_in[8];
    const float* c1w = (const float*)d_in[9];
    const float* c1b = (const float*)d_in[10];
    const float* c2w = (const float*)d_in[11];
    const float* c2b = (const float*)d_in[12];

    float* eout    = (float*)d_out;
    float* partsum = (float*)d_ws;            // NROW*PB = 848 floats

    k_wavenet<<<NROW * PB, NT, 0, stream>>>(x, cw, cb, fw, fb, gw, gb, rw, rb,
                                            c1w, c1b, c2w, c2b, eout, partsum);
    k_scale<<<NB2, 256, 0, stream>>>(eout, partsum);
}

// Round 12
// 144.759 us; speedup vs baseline: 1.0572x; 1.0572x over previous
//
#include <hip/hip_runtime.h>
#include <cmath>

#define T_LEN 262144
#define NROW 8
#define NL 30
#define NT 512
#define PPT 3                        /* f32x2 pairs per thread */
#define EXT (NT * PPT * 2)           /* 3072 positions */
#define HALO 576
#define TILE (EXT - HALO)            /* 2496 */
#define PB ((T_LEN + TILE - 1) / TILE)   /* 106 tiles per row */
#define PAD 32
#define CH 4096                      /* elements per scale chunk */
#define RB (T_LEN / CH)              /* 64 chunks per row */
#define NB2 (NROW * RB)              /* 512 */

#define NEG2LOG2E -2.885390082f      /* -2*log2(e) */
#define NEGLOG2E  -1.4426950409f     /* -log2(e)  */

#if __has_builtin(__builtin_amdgcn_exp2f)
#define EXP2(x) __builtin_amdgcn_exp2f(x)
#else
#define EXP2(x) __expf(0.6931471805599453f * (x))
#endif

typedef float f32x2 __attribute__((ext_vector_type(2)));

__device__ __forceinline__ float fast_rcp(float x) { return __builtin_amdgcn_rcpf(x); }

__device__ __forceinline__ f32x2 exp2v(f32x2 x) {
    f32x2 r; r.x = EXP2(x.x); r.y = EXP2(x.y); return r;
}
__device__ __forceinline__ f32x2 rcpv(f32x2 x) {
    f32x2 r; r.x = fast_rcp(x.x); r.y = fast_rcp(x.y); return r;
}

// One gated residual layer over f32x2 pairs (packed fp32 math), split into
// an explicit LOAD phase (all 12 tap pairs batched -> MLP) and a COMPUTE
// phase (3 independent chains). D even; CUT = progressive dead-halo bound.
template<int D, int CUT, bool WB>
__device__ __forceinline__ void layerv(
    int k,
    const float* __restrict__ fw, const float* __restrict__ fb,
    const float* __restrict__ gw, const float* __restrict__ gb,
    const float* __restrict__ rw, const float* __restrict__ rb,
    const float* __restrict__ src, float* __restrict__ dst,
    f32x2 (&h)[PPT], f32x2 (&skip)[PPT], int tid)
{
    const float f0 = fw[k*5+0], f1 = fw[k*5+1], f2 = fw[k*5+2], f3 = fw[k*5+3], f4 = fw[k*5+4];
    const float fbk = fb[k];
    const float g0 = gw[k*5+0], g1 = gw[k*5+1], g2 = gw[k*5+2], g3 = gw[k*5+3], g4 = gw[k*5+4];
    const float gbk = gb[k];
    const float rwk = rw[k], rbk = rb[k];

    // ---- load phase: batch all taps (12 x ds_read_b64 in flight) ----
    f32x2 t0[PPT], t1[PPT], t2[PPT], t3[PPT];
    #pragma unroll
    for (int p = 0; p < PPT; ++p) {
        const int i2 = 2 * (tid + p * NT);
        t0[p] = *(const f32x2*)&src[i2 - 4*D];
        t1[p] = *(const f32x2*)&src[i2 - 3*D];
        t2[p] = *(const f32x2*)&src[i2 - 2*D];
        t3[p] = *(const f32x2*)&src[i2 -   D];
    }

    // ---- compute phase: 3 independent chains ----
    #pragma unroll
    for (int p = 0; p < PPT; ++p) {
        const int i2 = 2 * (tid + p * NT);
        if (2 * p * NT < CUT) {               // only pair 0 can be dead
            if ((i2 + 1) < CUT) continue;     // dead halo pair (stays dead)
        }
        const f32x2 v4 = h[p];

        f32x2 af = fbk + f0 * t0[p];
        af = f1 * t1[p] + af;
        af = f2 * t2[p] + af;
        af = f3 * t3[p] + af;
        af = f4 * v4    + af;
        f32x2 ag = gbk + g0 * t0[p];
        ag = g1 * t1[p] + ag;
        ag = g2 * t2[p] + ag;
        ag = g3 * t3[p] + ag;
        ag = g4 * v4    + ag;

        // z = tanh(af)*sigmoid(ag) = (1-u)/((1+u)(1+w)), u=e^{-2af}, w=e^{-ag}
        const f32x2 u = exp2v(af * NEG2LOG2E);
        const f32x2 w = exp2v(ag * NEGLOG2E);
        const f32x2 num = 1.0f - u;
        const f32x2 den = (1.0f + u) * (1.0f + w);
        const f32x2 z = num * rcpv(den);
        skip[p] += z;
        if (WB) {
            h[p] = (z * rwk + rbk) + v4;
            *(f32x2*)&dst[i2] = h[p];
        }
    }
    if (WB) __syncthreads();
}

// d=1 gated layer (layer 0): odd tap offsets -> neighbor-component reuse.
__device__ __forceinline__ void layer_d1(
    const float* __restrict__ fw, const float* __restrict__ fb,
    const float* __restrict__ gw, const float* __restrict__ gb,
    const float* __restrict__ rw, const float* __restrict__ rb,
    const float* __restrict__ src, float* __restrict__ dst,
    f32x2 (&h)[PPT], f32x2 (&skip)[PPT], int tid)
{
    const float f0 = fw[0], f1 = fw[1], f2 = fw[2], f3 = fw[3], f4 = fw[4];
    const float fbk = fb[0];
    const float g0 = gw[0], g1 = gw[1], g2 = gw[2], g3 = gw[3], g4 = gw[4];
    const float gbk = gb[0];
    const float rwk = rw[0], rbk = rb[0];

    f32x2 ta[PPT], tb[PPT];
    #pragma unroll
    for (int p = 0; p < PPT; ++p) {
        const int i2 = 2 * (tid + p * NT);
        ta[p] = *(const f32x2*)&src[i2 - 4];
        tb[p] = *(const f32x2*)&src[i2 - 2];
    }
    #pragma unroll
    for (int p = 0; p < PPT; ++p) {
        const f32x2 a = ta[p], b = tb[p], c = h[p];
        const int i2 = 2 * (tid + p * NT);
        f32x2 v0, v1, v2, v3;
        v0.x = a.x; v0.y = a.y;
        v1.x = a.y; v1.y = b.x;
        v2.x = b.x; v2.y = b.y;
        v3.x = b.y; v3.y = c.x;

        f32x2 af = fbk + f0 * v0;
        af = f1 * v1 + af;
        af = f2 * v2 + af;
        af = f3 * v3 + af;
        af = f4 * c  + af;
        f32x2 ag = gbk + g0 * v0;
        ag = g1 * v1 + ag;
        ag = g2 * v2 + ag;
        ag = g3 * v3 + ag;
        ag = g4 * c  + ag;

        const f32x2 u = exp2v(af * NEG2LOG2E);
        const f32x2 w = exp2v(ag * NEGLOG2E);
        const f32x2 num = 1.0f - u;
        const f32x2 den = (1.0f + u) * (1.0f + w);
        const f32x2 z = num * rcpv(den);
        skip[p] += z;
        h[p] = (z * rwk + rbk) + c;
        *(f32x2*)&dst[i2] = h[p];
    }
    __syncthreads();
}

// ---------------------------------------------------------------------------
__global__ __launch_bounds__(NT, 8)
void k_wavenet(const float* __restrict__ x,
               const float* __restrict__ cw,  const float* __restrict__ cb,
               const float* __restrict__ fw,  const float* __restrict__ fb,
               const float* __restrict__ gw,  const float* __restrict__ gb,
               const float* __restrict__ rw,  const float* __restrict__ rb,
               const float* __restrict__ c1w, const float* __restrict__ c1b,
               const float* __restrict__ c2w, const float* __restrict__ c2b,
               float* __restrict__ eout, float* __restrict__ partsum)
{
    __shared__ __align__(16) float hrawA[PAD + EXT];
    __shared__ __align__(16) float hrawB[PAD + EXT];
    __shared__ float reds[NT / 64];
    float* bufA = hrawA + PAD;
    float* bufB = hrawB + PAD;

    const int tid  = threadIdx.x;
    const int row  = blockIdx.x / PB;
    const int tile = blockIdx.x % PB;
    const int t0   = tile * TILE;

    if (tid < PAD) { hrawA[tid] = 0.0f; hrawB[tid] = 0.0f; }

    const float* xr = x + (size_t)row * T_LEN;
    f32x2 h[PPT], skip[PPT];
    #pragma unroll
    for (int p = 0; p < PPT; ++p) {
        const int i2 = 2 * (tid + p * NT);
        const int g = t0 - HALO + i2;
        f32x2 v;
        v.x = (g     >= 0 && g     < T_LEN) ? xr[g]     : 0.0f;
        v.y = (g + 1 >= 0 && g + 1 < T_LEN) ? xr[g + 1] : 0.0f;
        *(f32x2*)&bufA[i2] = v;
        h[p] = v;
        skip[p].x = 0.0f; skip[p].y = 0.0f;
    }
    __syncthreads();

    // initial causal conv (d=1): A -> B
    {
        const float w0 = cw[0], w1 = cw[1], w2 = cw[2], w3 = cw[3], w4 = cw[4];
        const float b  = cb[0];
        f32x2 ta[PPT], tb[PPT];
        #pragma unroll
        for (int p = 0; p < PPT; ++p) {
            const int i2 = 2 * (tid + p * NT);
            ta[p] = *(const f32x2*)&bufA[i2 - 4];
            tb[p] = *(const f32x2*)&bufA[i2 - 2];
        }
        #pragma unroll
        for (int p = 0; p < PPT; ++p) {
            const int i2 = 2 * (tid + p * NT);
            const f32x2 a = ta[p], bb = tb[p], c = h[p];
            f32x2 v0, v1, v2, v3;
            v0.x = a.x;  v0.y = a.y;
            v1.x = a.y;  v1.y = bb.x;
            v2.x = bb.x; v2.y = bb.y;
            v3.x = bb.y; v3.y = c.x;
            f32x2 acc = b + w0 * v0;
            acc = w1 * v1 + acc;
            acc = w2 * v2 + acc;
            acc = w3 * v3 + acc;
            acc = w4 * c  + acc;
            h[p] = acc;
            *(f32x2*)&bufB[i2] = acc;
        }
        __syncthreads();
    }

    // 30 layers, fully unrolled; ping-pong B->A->B...; literal k and CUT.
    layer_d1(fw, fb, gw, gb, rw, rb, bufB, bufA, h, skip, tid);
    layerv<2,  16, true >( 1, fw, fb, gw, gb, rw, rb, bufA, bufB, h, skip, tid);
    layerv<4,  32, true >( 2, fw, fb, gw, gb, rw, rb, bufB, bufA, h, skip, tid);
    layerv<8,  64, true >( 3, fw, fb, gw, gb, rw, rb, bufA, bufB, h, skip, tid);
    layerv<6,  88, true >( 4, fw, fb, gw, gb, rw, rb, bufB, bufA, h, skip, tid);
    layerv<2,  96, true >( 5, fw, fb, gw, gb, rw, rb, bufA, bufB, h, skip, tid);
    layerv<4, 112, true >( 6, fw, fb, gw, gb, rw, rb, bufB, bufA, h, skip, tid);
    layerv<8, 144, true >( 7, fw, fb, gw, gb, rw, rb, bufA, bufB, h, skip, tid);
    layerv<6, 168, true >( 8, fw, fb, gw, gb, rw, rb, bufB, bufA, h, skip, tid);
    layerv<2, 176, true >( 9, fw, fb, gw, gb, rw, rb, bufA, bufB, h, skip, tid);
    layerv<4, 192, true >(10, fw, fb, gw, gb, rw, rb, bufB, bufA, h, skip, tid);
    layerv<8, 224, true >(11, fw, fb, gw, gb, rw, rb, bufA, bufB, h, skip, tid);
    layerv<6, 248, true >(12, fw, fb, gw, gb, rw, rb, bufB, bufA, h, skip, tid);
    layerv<2, 256, true >(13, fw, fb, gw, gb, rw, rb, bufA, bufB, h, skip, tid);
    layerv<4, 272, true >(14, fw, fb, gw, gb, rw, rb, bufB, bufA, h, skip, tid);
    layerv<8, 304, true >(15, fw, fb, gw, gb, rw, rb, bufA, bufB, h, skip, tid);
    layerv<6, 328, true >(16, fw, fb, gw, gb, rw, rb, bufB, bufA, h, skip, tid);
    layerv<2, 336, true >(17, fw, fb, gw, gb, rw, rb, bufA, bufB, h, skip, tid);
    layerv<4, 352, true >(18, fw, fb, gw, gb, rw, rb, bufB, bufA, h, skip, tid);
    layerv<8, 384, true >(19, fw, fb, gw, gb, rw, rb, bufA, bufB, h, skip, tid);
    layerv<6, 408, true >(20, fw, fb, gw, gb, rw, rb, bufB, bufA, h, skip, tid);
    layerv<2, 416, true >(21, fw, fb, gw, gb, rw, rb, bufA, bufB, h, skip, tid);
    layerv<4, 432, true >(22, fw, fb, gw, gb, rw, rb, bufB, bufA, h, skip, tid);
    layerv<8, 464, true >(23, fw, fb, gw, gb, rw, rb, bufA, bufB, h, skip, tid);
    layerv<6, 488, true >(24, fw, fb, gw, gb, rw, rb, bufB, bufA, h, skip, tid);
    layerv<2, 496, true >(25, fw, fb, gw, gb, rw, rb, bufA, bufB, h, skip, tid);
    layerv<4, 512, true >(26, fw, fb, gw, gb, rw, rb, bufB, bufA, h, skip, tid);
    layerv<8, 544, true >(27, fw, fb, gw, gb, rw, rb, bufA, bufB, h, skip, tid);
    layerv<6, 568, true >(28, fw, fb, gw, gb, rw, rb, bufB, bufA, h, skip, tid);
    layerv<2, 576, false>(29, fw, fb, gw, gb, rw, rb, bufA, bufB, h, skip, tid);

    // epilogue: 1x1 convs + mu-law expand; write e = exp(v); partial sum
    const float w1 = c1w[0], b1 = c1b[0], w2 = c2w[0], b2 = c2b[0];
    float s = 0.0f;
    float* er = eout + (size_t)row * T_LEN;
    #pragma unroll
    for (int p = 0; p < PPT; ++p) {
        const int i2 = 2 * (tid + p * NT);
        if (i2 >= HALO) {
            const int t = t0 + i2 - HALO;
            if (t < T_LEN) {
                f32x2 sk = skip[p];
                float ox = fmaf(fmaxf(sk.x, 0.0f), w1, b1);
                float oy = fmaf(fmaxf(sk.y, 0.0f), w1, b1);
                ox = fmaf(fmaxf(ox, 0.0f), w2, b2);
                oy = fmaf(fmaxf(oy, 0.0f), w2, b2);
                float vx = fmaf(EXP2(8.0f * fabsf(ox)), (1.0f/255.0f), -(1.0f/255.0f));
                float vy = fmaf(EXP2(8.0f * fabsf(oy)), (1.0f/255.0f), -(1.0f/255.0f));
                vx = copysignf(vx, ox);
                vy = copysignf(vy, oy);
                const float ex = __expf(vx);
                const float ey = __expf(vy);
                f32x2 e; e.x = ex; e.y = ey;
                *(f32x2*)&er[t] = e;
                s += ex + ey;
            }
        }
    }
    #pragma unroll
    for (int off = 32; off >= 1; off >>= 1) s += __shfl_xor(s, off, 64);
    if ((tid & 63) == 0) reds[tid >> 6] = s;
    __syncthreads();
    if (tid == 0) {
        float ss = 0.0f;
        #pragma unroll
        for (int w = 0; w < NT / 64; ++w) ss += reds[w];
        partsum[blockIdx.x] = ss;
    }
}

// ---------------------------------------------------------------------------
__global__ __launch_bounds__(256)
void k_scale(float* __restrict__ ebuf, const float* __restrict__ partsum)
{
    const int tid = threadIdx.x;
    const int row = blockIdx.x / RB;

    __shared__ float red[4];
    float s = 0.0f;
    for (int j = tid; j < PB; j += 256) s += partsum[row * PB + j];
    #pragma unroll
    for (int off = 32; off >= 1; off >>= 1) s += __shfl_xor(s, off, 64);
    if ((tid & 63) == 0) red[tid >> 6] = s;
    __syncthreads();
    const float tot = (red[0] + red[1]) + (red[2] + red[3]);
    const float inv = 1.0f / tot;

    float4* vp = (float4*)(ebuf + (size_t)blockIdx.x * CH);
    #pragma unroll
    for (int q = 0; q < 4; ++q) {
        float4 v = vp[tid + q * 256];
        v.x *= inv; v.y *= inv; v.z *= inv; v.w *= inv;
        vp[tid + q * 256] = v;
    }
}

// ---------------------------------------------------------------------------
extern "C" void kernel_launch(void* const* d_in, const int* in_sizes, int n_in,
                              void* d_out, int out_size, void* d_ws, size_t ws_size,
                              hipStream_t stream)
{
    const float* x   = (const float*)d_in[0];
    const float* cw  = (const float*)d_in[1];
    const float* cb  = (const float*)d_in[2];
    const float* fw  = (const float*)d_in[3];
    const float* fb  = (const float*)d_in[4];
    const float* gw  = (const float*)d_in[5];
    const float* gb  = (const float*)d_in[6];
    const float* rw  = (const float*)d_in[7];
    const float* rb  = (const float*)d_in[8];
    const float* c1w = (const float*)d_in[9];
    const float* c1b = (const float*)d_in[10];
    const float* c2w = (const float*)d_in[11];
    const float* c2b = (const float*)d_in[12];

    float* eout    = (float*)d_out;
    float* partsum = (float*)d_ws;            // NROW*PB = 848 floats

    k_wavenet<<<NROW * PB, NT, 0, stream>>>(x, cw, cb, fw, fb, gw, gb, rw, rb,
                                            c1w, c1b, c2w, c2b, eout, partsum);
    k_scale<<<NB2, 256, 0, stream>>>(eout, partsum);
}

// Round 13
// 144.338 us; speedup vs baseline: 1.0603x; 1.0029x over previous
//
#include <hip/hip_runtime.h>
#include <cmath>

#define T_LEN 262144
#define NROW 8
#define NL 30
#define NT 256
#define PPT 4                        /* f32x2 pairs per thread */
#define EXT (NT * PPT * 2)           /* 2048 positions */
#define HALO 576
#define TILE (EXT - HALO)            /* 1472 */
#define PB ((T_LEN + TILE - 1) / TILE)   /* 179 tiles per row */
#define PAD 32
#define CH 4096                      /* elements per scale chunk */
#define RB (T_LEN / CH)              /* 64 chunks per row */
#define NB2 (NROW * RB)              /* 512 */

#define NEG2LOG2E -2.885390082f      /* -2*log2(e) */
#define NEGLOG2E  -1.4426950409f     /* -log2(e)  */

#if __has_builtin(__builtin_amdgcn_exp2f)
#define EXP2(x) __builtin_amdgcn_exp2f(x)
#else
#define EXP2(x) __expf(0.6931471805599453f * (x))
#endif

typedef float f32x2 __attribute__((ext_vector_type(2)));

__device__ __forceinline__ float fast_rcp(float x) { return __builtin_amdgcn_rcpf(x); }

__device__ __forceinline__ f32x2 exp2v(f32x2 x) {
    f32x2 r; r.x = EXP2(x.x); r.y = EXP2(x.y); return r;
}
__device__ __forceinline__ f32x2 rcpv(f32x2 x) {
    f32x2 r; r.x = fast_rcp(x.x); r.y = fast_rcp(x.y); return r;
}

// One gated residual layer over f32x2 pairs (packed fp32 math).
// D even; CUT = progressive dead-halo bound (compile-time).
template<int D, int CUT, bool WB>
__device__ __forceinline__ void layerv(
    int k,
    const float* __restrict__ fw, const float* __restrict__ fb,
    const float* __restrict__ gw, const float* __restrict__ gb,
    const float* __restrict__ rw, const float* __restrict__ rb,
    const float* __restrict__ src, float* __restrict__ dst,
    f32x2 (&h)[PPT], f32x2 (&skip)[PPT], int tid)
{
    const float f0 = fw[k*5+0], f1 = fw[k*5+1], f2 = fw[k*5+2], f3 = fw[k*5+3], f4 = fw[k*5+4];
    const float fbk = fb[k];
    const float g0 = gw[k*5+0], g1 = gw[k*5+1], g2 = gw[k*5+2], g3 = gw[k*5+3], g4 = gw[k*5+4];
    const float gbk = gb[k];
    const float rwk = rw[k], rbk = rb[k];

    #pragma unroll
    for (int p = 0; p < PPT; ++p) {
        const int i2 = 2 * (tid + p * NT);
        if (2 * p * NT < CUT) {               // pair may be dead (stays dead)
            if ((i2 + 1) < CUT) continue;
        }
        const f32x2 v0 = *(const f32x2*)&src[i2 - 4*D];
        const f32x2 v1 = *(const f32x2*)&src[i2 - 3*D];
        const f32x2 v2 = *(const f32x2*)&src[i2 - 2*D];
        const f32x2 v3 = *(const f32x2*)&src[i2 -   D];
        const f32x2 v4 = h[p];

        f32x2 af = fbk + f0 * v0;
        af = f1 * v1 + af;
        af = f2 * v2 + af;
        af = f3 * v3 + af;
        af = f4 * v4 + af;
        f32x2 ag = gbk + g0 * v0;
        ag = g1 * v1 + ag;
        ag = g2 * v2 + ag;
        ag = g3 * v3 + ag;
        ag = g4 * v4 + ag;

        // z = tanh(af)*sigmoid(ag) = (1-u)/((1+u)(1+w)), u=e^{-2af}, w=e^{-ag}
        const f32x2 u = exp2v(af * NEG2LOG2E);
        const f32x2 w = exp2v(ag * NEGLOG2E);
        const f32x2 num = 1.0f - u;
        const f32x2 den = (1.0f + u) * (1.0f + w);
        const f32x2 z = num * rcpv(den);
        skip[p] += z;
        if (WB) {
            h[p] = (z * rwk + rbk) + v4;
            *(f32x2*)&dst[i2] = h[p];
        }
    }
    if (WB) __syncthreads();
}

// d=1 gated layer (layer 0): odd tap offsets -> neighbor-component reuse.
__device__ __forceinline__ void layer_d1(
    const float* __restrict__ fw, const float* __restrict__ fb,
    const float* __restrict__ gw, const float* __restrict__ gb,
    const float* __restrict__ rw, const float* __restrict__ rb,
    const float* __restrict__ src, float* __restrict__ dst,
    f32x2 (&h)[PPT], f32x2 (&skip)[PPT], int tid)
{
    const float f0 = fw[0], f1 = fw[1], f2 = fw[2], f3 = fw[3], f4 = fw[4];
    const float fbk = fb[0];
    const float g0 = gw[0], g1 = gw[1], g2 = gw[2], g3 = gw[3], g4 = gw[4];
    const float gbk = gb[0];
    const float rwk = rw[0], rbk = rb[0];

    #pragma unroll
    for (int p = 0; p < PPT; ++p) {
        const int i2 = 2 * (tid + p * NT);
        const f32x2 a = *(const f32x2*)&src[i2 - 4];
        const f32x2 b = *(const f32x2*)&src[i2 - 2];
        const f32x2 c = h[p];
        f32x2 v0, v1, v2, v3;
        v0.x = a.x; v0.y = a.y;
        v1.x = a.y; v1.y = b.x;
        v2.x = b.x; v2.y = b.y;
        v3.x = b.y; v3.y = c.x;

        f32x2 af = fbk + f0 * v0;
        af = f1 * v1 + af;
        af = f2 * v2 + af;
        af = f3 * v3 + af;
        af = f4 * c  + af;
        f32x2 ag = gbk + g0 * v0;
        ag = g1 * v1 + ag;
        ag = g2 * v2 + ag;
        ag = g3 * v3 + ag;
        ag = g4 * c  + ag;

        const f32x2 u = exp2v(af * NEG2LOG2E);
        const f32x2 w = exp2v(ag * NEGLOG2E);
        const f32x2 num = 1.0f - u;
        const f32x2 den = (1.0f + u) * (1.0f + w);
        const f32x2 z = num * rcpv(den);
        skip[p] += z;
        h[p] = (z * rwk + rbk) + c;
        *(f32x2*)&dst[i2] = h[p];
    }
    __syncthreads();
}

// ---------------------------------------------------------------------------
__global__ __launch_bounds__(NT, 8)
void k_wavenet(const float* __restrict__ x,
               const float* __restrict__ cw,  const float* __restrict__ cb,
               const float* __restrict__ fw,  const float* __restrict__ fb,
               const float* __restrict__ gw,  const float* __restrict__ gb,
               const float* __restrict__ rw,  const float* __restrict__ rb,
               const float* __restrict__ c1w, const float* __restrict__ c1b,
               const float* __restrict__ c2w, const float* __restrict__ c2b,
               float* __restrict__ eout, float* __restrict__ partsum)
{
    __shared__ __align__(16) float hrawA[PAD + EXT];
    __shared__ __align__(16) float hrawB[PAD + EXT];
    __shared__ float reds[NT / 64];
    float* bufA = hrawA + PAD;
    float* bufB = hrawB + PAD;

    const int tid  = threadIdx.x;
    const int row  = blockIdx.x / PB;
    const int tile = blockIdx.x % PB;
    const int t0   = tile * TILE;

    if (tid < PAD) { hrawA[tid] = 0.0f; hrawB[tid] = 0.0f; }

    const float* xr = x + (size_t)row * T_LEN;
    f32x2 h[PPT], skip[PPT];
    #pragma unroll
    for (int p = 0; p < PPT; ++p) {
        const int i2 = 2 * (tid + p * NT);
        const int g = t0 - HALO + i2;
        f32x2 v;
        v.x = (g     >= 0 && g     < T_LEN) ? xr[g]     : 0.0f;
        v.y = (g + 1 >= 0 && g + 1 < T_LEN) ? xr[g + 1] : 0.0f;
        *(f32x2*)&bufA[i2] = v;
        h[p] = v;
        skip[p].x = 0.0f; skip[p].y = 0.0f;
    }
    __syncthreads();

    // initial causal conv (d=1): A -> B
    {
        const float w0 = cw[0], w1 = cw[1], w2 = cw[2], w3 = cw[3], w4 = cw[4];
        const float b  = cb[0];
        #pragma unroll
        for (int p = 0; p < PPT; ++p) {
            const int i2 = 2 * (tid + p * NT);
            const f32x2 a  = *(const f32x2*)&bufA[i2 - 4];
            const f32x2 bb = *(const f32x2*)&bufA[i2 - 2];
            const f32x2 c  = h[p];
            f32x2 v0, v1, v2, v3;
            v0.x = a.x;  v0.y = a.y;
            v1.x = a.y;  v1.y = bb.x;
            v2.x = bb.x; v2.y = bb.y;
            v3.x = bb.y; v3.y = c.x;
            f32x2 acc = b + w0 * v0;
            acc = w1 * v1 + acc;
            acc = w2 * v2 + acc;
            acc = w3 * v3 + acc;
            acc = w4 * c  + acc;
            h[p] = acc;
            *(f32x2*)&bufB[i2] = acc;
        }
        __syncthreads();
    }

    // 30 layers, fully unrolled; ping-pong B->A->B...; literal k and CUT.
    layer_d1(fw, fb, gw, gb, rw, rb, bufB, bufA, h, skip, tid);
    layerv<2,  16, true >( 1, fw, fb, gw, gb, rw, rb, bufA, bufB, h, skip, tid);
    layerv<4,  32, true >( 2, fw, fb, gw, gb, rw, rb, bufB, bufA, h, skip, tid);
    layerv<8,  64, true >( 3, fw, fb, gw, gb, rw, rb, bufA, bufB, h, skip, tid);
    layerv<6,  88, true >( 4, fw, fb, gw, gb, rw, rb, bufB, bufA, h, skip, tid);
    layerv<2,  96, true >( 5, fw, fb, gw, gb, rw, rb, bufA, bufB, h, skip, tid);
    layerv<4, 112, true >( 6, fw, fb, gw, gb, rw, rb, bufB, bufA, h, skip, tid);
    layerv<8, 144, true >( 7, fw, fb, gw, gb, rw, rb, bufA, bufB, h, skip, tid);
    layerv<6, 168, true >( 8, fw, fb, gw, gb, rw, rb, bufB, bufA, h, skip, tid);
    layerv<2, 176, true >( 9, fw, fb, gw, gb, rw, rb, bufA, bufB, h, skip, tid);
    layerv<4, 192, true >(10, fw, fb, gw, gb, rw, rb, bufB, bufA, h, skip, tid);
    layerv<8, 224, true >(11, fw, fb, gw, gb, rw, rb, bufA, bufB, h, skip, tid);
    layerv<6, 248, true >(12, fw, fb, gw, gb, rw, rb, bufB, bufA, h, skip, tid);
    layerv<2, 256, true >(13, fw, fb, gw, gb, rw, rb, bufA, bufB, h, skip, tid);
    layerv<4, 272, true >(14, fw, fb, gw, gb, rw, rb, bufB, bufA, h, skip, tid);
    layerv<8, 304, true >(15, fw, fb, gw, gb, rw, rb, bufA, bufB, h, skip, tid);
    layerv<6, 328, true >(16, fw, fb, gw, gb, rw, rb, bufB, bufA, h, skip, tid);
    layerv<2, 336, true >(17, fw, fb, gw, gb, rw, rb, bufA, bufB, h, skip, tid);
    layerv<4, 352, true >(18, fw, fb, gw, gb, rw, rb, bufB, bufA, h, skip, tid);
    layerv<8, 384, true >(19, fw, fb, gw, gb, rw, rb, bufA, bufB, h, skip, tid);
    layerv<6, 408, true >(20, fw, fb, gw, gb, rw, rb, bufB, bufA, h, skip, tid);
    layerv<2, 416, true >(21, fw, fb, gw, gb, rw, rb, bufA, bufB, h, skip, tid);
    layerv<4, 432, true >(22, fw, fb, gw, gb, rw, rb, bufB, bufA, h, skip, tid);
    layerv<8, 464, true >(23, fw, fb, gw, gb, rw, rb, bufA, bufB, h, skip, tid);
    layerv<6, 488, true >(24, fw, fb, gw, gb, rw, rb, bufB, bufA, h, skip, tid);
    layerv<2, 496, true >(25, fw, fb, gw, gb, rw, rb, bufA, bufB, h, skip, tid);
    layerv<4, 512, true >(26, fw, fb, gw, gb, rw, rb, bufB, bufA, h, skip, tid);
    layerv<8, 544, true >(27, fw, fb, gw, gb, rw, rb, bufA, bufB, h, skip, tid);
    layerv<6, 568, true >(28, fw, fb, gw, gb, rw, rb, bufB, bufA, h, skip, tid);
    layerv<2, 576, false>(29, fw, fb, gw, gb, rw, rb, bufA, bufB, h, skip, tid);

    // epilogue: 1x1 convs + mu-law expand; write e = exp(v); partial sum
    const float w1 = c1w[0], b1 = c1b[0], w2 = c2w[0], b2 = c2b[0];
    float s = 0.0f;
    float* er = eout + (size_t)row * T_LEN;
    #pragma unroll
    for (int p = 0; p < PPT; ++p) {
        const int i2 = 2 * (tid + p * NT);
        if (i2 >= HALO) {
            const int t = t0 + i2 - HALO;
            if (t < T_LEN) {
                f32x2 sk = skip[p];
                float ox = fmaf(fmaxf(sk.x, 0.0f), w1, b1);
                float oy = fmaf(fmaxf(sk.y, 0.0f), w1, b1);
                ox = fmaf(fmaxf(ox, 0.0f), w2, b2);
                oy = fmaf(fmaxf(oy, 0.0f), w2, b2);
                float vx = fmaf(EXP2(8.0f * fabsf(ox)), (1.0f/255.0f), -(1.0f/255.0f));
                float vy = fmaf(EXP2(8.0f * fabsf(oy)), (1.0f/255.0f), -(1.0f/255.0f));
                vx = copysignf(vx, ox);
                vy = copysignf(vy, oy);
                const float ex = __expf(vx);
                const float ey = __expf(vy);
                f32x2 e; e.x = ex; e.y = ey;
                *(f32x2*)&er[t] = e;
                s += ex + ey;
            }
        }
    }
    #pragma unroll
    for (int off = 32; off >= 1; off >>= 1) s += __shfl_xor(s, off, 64);
    if ((tid & 63) == 0) reds[tid >> 6] = s;
    __syncthreads();
    if (tid == 0) {
        float ss = 0.0f;
        #pragma unroll
        for (int w = 0; w < NT / 64; ++w) ss += reds[w];
        partsum[blockIdx.x] = ss;
    }
}

// ---------------------------------------------------------------------------
__global__ __launch_bounds__(256)
void k_scale(float* __restrict__ ebuf, const float* __restrict__ partsum)
{
    const int tid = threadIdx.x;
    const int row = blockIdx.x / RB;

    __shared__ float red[4];
    float s = 0.0f;
    for (int j = tid; j < PB; j += 256) s += partsum[row * PB + j];
    #pragma unroll
    for (int off = 32; off >= 1; off >>= 1) s += __shfl_xor(s, off, 64);
    if ((tid & 63) == 0) red[tid >> 6] = s;
    __syncthreads();
    const float tot = (red[0] + red[1]) + (red[2] + red[3]);
    const float inv = 1.0f / tot;

    float4* vp = (float4*)(ebuf + (size_t)blockIdx.x * CH);
    #pragma unroll
    for (int q = 0; q < 4; ++q) {
        float4 v = vp[tid + q * 256];
        v.x *= inv; v.y *= inv; v.z *= inv; v.w *= inv;
        vp[tid + q * 256] = v;
    }
}

// ---------------------------------------------------------------------------
extern "C" void kernel_launch(void* const* d_in, const int* in_sizes, int n_in,
                              void* d_out, int out_size, void* d_ws, size_t ws_size,
                              hipStream_t stream)
{
    const float* x   = (const float*)d_in[0];
    const float* cw  = (const float*)d_in[1];
    const float* cb  = (const float*)d_in[2];
    const float* fw  = (const float*)d_in[3];
    const float* fb  = (const float*)d_in[4];
    const float* gw  = (const float*)d_in[5];
    const float* gb  = (const float*)d_in[6];
    const float* rw  = (const float*)d_in[7];
    const float* rb  = (const float*)d_in[8];
    const float* c1w = (const float*)d_in[9];
    const float* c1b = (const float*)d_in[10];
    const float* c2w = (const float*)d_in[11];
    const float* c2b = (const float*)d_in[12];

    float* eout    = (float*)d_out;
    float* partsum = (float*)d_ws;            // NROW*PB = 1432 floats

    k_wavenet<<<NROW * PB, NT, 0, stream>>>(x, cw, cb, fw, fb, gw, gb, rw, rb,
                                            c1w, c1b, c2w, c2b, eout, partsum);
    k_scale<<<NB2, 256, 0, stream>>>(eout, partsum);
}